// Round 5
// baseline (4340.031 us; speedup 1.0000x reference)
//
#include <hip/hip_runtime.h>

// B=8, T=1024, E=768, H=12.
// Round 9: all GEMMs now use the pure global_load_lds path (B^T row-major).
//  - K/V transposed per (head,chunk) by t_hl (LDS-tiled, u16x2) so scores/Z
//    drop the scalar k-major B staging.
//  - g_qkv grid reordered z-innermost: the 18 blocks sharing an A-panel
//    dispatch adjacently -> panel fetched ~8x (once per XCD) not ~18x.
//  - __launch_bounds__(256,4): 4 blocks/CU (LDS 32KB, VGPR<=128).

typedef __bf16 bf16x8 __attribute__((ext_vector_type(8)));
typedef float  f32x4  __attribute__((ext_vector_type(4)));
typedef unsigned short u16;
typedef u16 u16x2 __attribute__((ext_vector_type(2)));
typedef u16 u16x4 __attribute__((ext_vector_type(4)));
typedef unsigned int u32;

#define RC 16   // row-chunks for 3-phase softmax

__device__ __forceinline__ float bf2f(u16 u) {
    union { u32 i; float f; } x; x.i = ((u32)u) << 16; return x.f;
}
__device__ __forceinline__ u16 f2bf(float f) {
    __bf16 h = (__bf16)f; union { __bf16 b; u16 u; } x; x.b = h; return x.u;
}
__device__ __forceinline__ void split2(float v, u16& h, u16& l) {
    h = f2bf(v); l = f2bf(v - bf2f(h));
}

__device__ __forceinline__ void gl16(const void* g, void* l) {
    __builtin_amdgcn_global_load_lds(
        (const __attribute__((address_space(1))) u32*)g,
        (__attribute__((address_space(3))) u32*)l, 16, 0, 0);
}

// ---------------- 128x128 split-bf16 core (B^T row-major only) ----------
// A: hi/lo row-major (M x K, lda). B^T: hi/lo row-major (N x K, ldb).
// Both staged via global_load_lds w16, source k pre-swizzled so the
// ds_read_b128 fragment reads are bank-even (verified conflict-free r4).
// WIN=1: per-lane A-source clamp to zero page for the quirky flat window.
template<int WIN>
__device__ __forceinline__ void core(
    const u16* __restrict__ Ah, const u16* __restrict__ Al,
    const u16* __restrict__ Bh, const u16* __restrict__ Bl,
    float* __restrict__ C, u16* __restrict__ Ch, u16* __restrict__ Cl,
    int K, int lda, int ldb, int ldc,
    long long aShift, long long aHi, const u16* __restrict__ zp,
    int mClip, int mode, int mtile, int kChunk, int kChunks, int n0)
{
    __shared__ u16 Ahs[4096], Als[4096], Bhs[4096], Bls[4096]; // 32 KiB

    const int tid = threadIdx.x, lane = tid & 63, w = tid >> 6;
    const int m0 = mtile * 128;
    const int wm = (w & 1) << 6, wn = (w >> 1) << 6;
    const int lr = lane & 15, lq = lane >> 4;
    const int rs = (lr >> 1) & 3;
    const int fro = (lq ^ rs) << 4;            // frag byte offset in row

    // DMA staging geometry: wave w covers LDS rows w*16..+15 (call 0)
    // and +64 (call 1); lane -> (row, 16B slot). Source k pre-swizzled.
    const int srow = (w << 4) + (lane >> 2);
    const int kk = (((lane & 3) ^ ((srow >> 1) & 3)) << 3);
    const int lds0 = (w << 10), lds1 = lds0 + 4096;

    f32x4 acc[4][4] = {};
    const int kLen = K / kChunks;
    const int kBeg = kChunk * kLen, kEnd = kBeg + kLen;

    auto stage = [&](int k0) {
        long long o1 = (long long)(m0 + srow) * lda + k0 + kk;
        long long o2 = o1 + (long long)64 * lda;
        const u16 *p1h = Ah + o1, *p1l = Al + o1;
        const u16 *p2h = Ah + o2, *p2l = Al + o2;
        if constexpr (WIN) {
            long long a1 = o1 + aShift, a2 = o2 + aShift;
            bool v1 = (a1 >= 0) && (a1 < aHi);
            bool v2 = (a2 >= 0) && (a2 < aHi);
            p1h = v1 ? Ah + a1 : zp;  p1l = v1 ? Al + a1 : zp;
            p2h = v2 ? Ah + a2 : zp;  p2l = v2 ? Al + a2 : zp;
        }
        gl16(p1h, (char*)Ahs + lds0);  gl16(p2h, (char*)Ahs + lds1);
        gl16(p1l, (char*)Als + lds0);  gl16(p2l, (char*)Als + lds1);
        long long b1 = (long long)(n0 + srow) * ldb + k0 + kk;
        long long b2 = b1 + (long long)64 * ldb;
        gl16(Bh + b1, (char*)Bhs + lds0);  gl16(Bh + b2, (char*)Bhs + lds1);
        gl16(Bl + b1, (char*)Bls + lds0);  gl16(Bl + b2, (char*)Bls + lds1);
    };

    for (int k0 = kBeg; k0 < kEnd; k0 += 32) {
        stage(k0);                       // async DMA into LDS
        __syncthreads();                 // drains vmcnt + lgkmcnt

        bf16x8 a_h[4], a_l[4];
#pragma unroll
        for (int mi = 0; mi < 4; ++mi) {
            int off = ((wm + (mi << 4) + lr) << 6) + fro;
            a_h[mi] = *(const bf16x8*)((char*)Ahs + off);
            a_l[mi] = *(const bf16x8*)((char*)Als + off);
        }
#pragma unroll
        for (int ni = 0; ni < 4; ++ni) {
            int off = ((wn + (ni << 4) + lr) << 6) + fro;
            bf16x8 b_h = *(const bf16x8*)((char*)Bhs + off);
            bf16x8 b_l = *(const bf16x8*)((char*)Bls + off);
#pragma unroll
            for (int mi = 0; mi < 4; ++mi) {
                acc[mi][ni] = __builtin_amdgcn_mfma_f32_16x16x32_bf16(a_h[mi], b_h, acc[mi][ni], 0, 0, 0);
                acc[mi][ni] = __builtin_amdgcn_mfma_f32_16x16x32_bf16(a_l[mi], b_h, acc[mi][ni], 0, 0, 0);
                acc[mi][ni] = __builtin_amdgcn_mfma_f32_16x16x32_bf16(a_h[mi], b_l, acc[mi][ni], 0, 0, 0);
            }
        }
        __syncthreads();
    }

    // Epilogue: C/D layout col = lane&15, row = (lane>>4)*4 + reg  [m89]
#pragma unroll
    for (int mi = 0; mi < 4; ++mi)
#pragma unroll
        for (int r = 0; r < 4; ++r) {
            int row = m0 + wm + (mi << 4) + (lq << 2) + r;
            if (row < mClip) {
#pragma unroll
                for (int ni = 0; ni < 4; ++ni) {
                    long long off = (long long)row * ldc + n0 + wn + (ni << 4) + lr;
                    float v = acc[mi][ni][r];
                    if (mode == 2)      atomicAdd(&C[off], v);
                    else if (mode == 1) { u16 hh, ll; split2(v, hh, ll); Ch[off] = hh; Cl[off] = ll; }
                    else                C[off] = v;
                }
            }
        }
}

// Fused QKV: grid (18, M/128); x = n-tile*3 + z (z innermost so the 18
// blocks sharing an A-panel dispatch adjacently across XCDs).
__global__ __launch_bounds__(256, 4)
void g_qkv(const u16* __restrict__ Xh, const u16* __restrict__ Xl,
           const u16* __restrict__ Wth, const u16* __restrict__ Wtl,
           u16* __restrict__ Qh, u16* __restrict__ Ql,
           u16* __restrict__ Kh, u16* __restrict__ Kl,
           u16* __restrict__ Vh, u16* __restrict__ Vl)
{
    const long long EE = 768LL * 768;
    int z  = blockIdx.x % 3;
    int n0 = (blockIdx.x / 3) * 128;
    const u16* bh = Wth + (long long)z * EE;
    const u16* bl = Wtl + (long long)z * EE;
    u16* ch = (z == 0) ? Qh : (z == 1) ? Kh : Vh;
    u16* cl = (z == 0) ? Ql : (z == 1) ? Kl : Vl;
    core<0>(Xh, Xl, bh, bl, nullptr, ch, cl, 768, 768, 768, 768,
            0, 0, nullptr, 1 << 30, 1, blockIdx.y, 0, 1, n0);
}

// Generic B^T GEMM (scores: B=Kt; Z: B=Vt), batched via z.
__global__ __launch_bounds__(256, 4)
void g_bt(const u16* __restrict__ Ah, const u16* __restrict__ Al,
          const u16* __restrict__ Bh, const u16* __restrict__ Bl,
          u16* __restrict__ Ch, u16* __restrict__ Cl,
          int K, int lda, int ldb, int ldc,
          long long sA, long long sB, long long sC)
{
    long long z = blockIdx.z;
    core<0>(Ah + z * sA, Al + z * sA, Bh + z * sB, Bl + z * sB,
            nullptr, Ch + z * sC, Cl + z * sC,
            K, lda, ldb, ldc, 0, 0, nullptr, 1 << 30, 1,
            blockIdx.y, 0, 1, blockIdx.x * 128);
}

// Final projection: windowed A (quirky flat reshape), k-split + atomics.
__global__ __launch_bounds__(256, 4)
void g_fin(const u16* __restrict__ Zh, const u16* __restrict__ Zl,
           const u16* __restrict__ WOth, const u16* __restrict__ WOtl,
           float* __restrict__ C, const u16* __restrict__ zp,
           long long aShift, int mClip, int kChunks)
{
    const long long TE_ = 786432;
    long long z = blockIdx.z;
    core<1>(Zh + z * TE_, Zl + z * TE_, WOth, WOtl, C + z * TE_,
            nullptr, nullptr, 9216, 9216, 9216, 768,
            aShift, TE_, zp, mClip, 2, 0, blockIdx.y, kChunks, blockIdx.x * 128);
}

// Batched flat transpose of hi/lo u16 buffers: out[c*R+r] = in[r*C+c].
// Tile 32(rows) x 64(cols); u16x2 loads/stores. grid (C/64, R/32, nb).
__global__ __launch_bounds__(256)
void t_hl(const u16* __restrict__ ih, const u16* __restrict__ il,
          u16* __restrict__ oh, u16* __restrict__ ol, int R, int C)
{
    long long zo = (long long)blockIdx.z * R * C;
    __shared__ u16 L[64][34];
    const int t = threadIdx.x, tx = t & 31, ty = t >> 5;
    const int r0 = blockIdx.y * 32, c0 = blockIdx.x * 64;
    const int orow = t >> 2;

    const u16* iv[2] = { ih + zo, il + zo };
    u16* ov[2] = { oh + zo, ol + zo };
#pragma unroll
    for (int p = 0; p < 2; ++p) {
        const u16* in = iv[p];  u16* out = ov[p];
#pragma unroll
        for (int i = 0; i < 4; ++i) {
            u16x2 v = *(const u16x2*)&in[(long long)(r0 + ty + 8 * i) * C + c0 + tx * 2];
            L[tx * 2][ty + 8 * i] = v[0];
            L[tx * 2 + 1][ty + 8 * i] = v[1];
        }
        __syncthreads();
#pragma unroll
        for (int i = 0; i < 4; ++i) {
            int j = (t & 3) * 4 + i;
            u16x2 wv;
            wv[0] = L[orow][j * 2];
            wv[1] = L[orow][j * 2 + 1];
            *(u16x2*)&out[(long long)(c0 + orow) * R + r0 + j * 2] = wv;
        }
        __syncthreads();
    }
}

// fp32 -> (hi,lo) bf16, flat.
__global__ void k_split(const float* __restrict__ s, u16* __restrict__ h,
                        u16* __restrict__ l, long long n)
{
    long long i = ((long long)blockIdx.x * blockDim.x + threadIdx.x) * 4;
    long long stride = (long long)gridDim.x * blockDim.x * 4;
    for (; i < n; i += stride) {
        float4 v = *(const float4*)(s + i);
        u16x4 hh, ll;
        u16 h0, l0, h1, l1, h2, l2, h3, l3;
        split2(v.x, h0, l0); split2(v.y, h1, l1);
        split2(v.z, h2, l2); split2(v.w, h3, l3);
        hh[0] = h0; hh[1] = h1; hh[2] = h2; hh[3] = h3;
        ll[0] = l0; ll[1] = l1; ll[2] = l2; ll[3] = l3;
        *(u16x4*)(h + i) = hh;
        *(u16x4*)(l + i) = ll;
    }
}

// fp32 (Ks x Ns) -> transposed (Ns x Ks) hi/lo bf16.
__global__ void k_tsplit(const float* __restrict__ s, u16* __restrict__ dh,
                         u16* __restrict__ dl, int Ks, int Ns)
{
    __shared__ float t[32][33];
    int tx = threadIdx.x & 31, ty = threadIdx.x >> 5;
    int kb = blockIdx.y << 5, nb_ = blockIdx.x << 5;
#pragma unroll
    for (int i = 0; i < 4; ++i)
        t[ty + 8 * i][tx] = s[(long long)(kb + ty + 8 * i) * Ns + nb_ + tx];
    __syncthreads();
#pragma unroll
    for (int i = 0; i < 4; ++i) {
        float v = t[tx][ty + 8 * i];
        long long o = (long long)(nb_ + ty + 8 * i) * Ks + kb + tx;
        u16 hh, ll; split2(v, hh, ll);
        dh[o] = hh; dl[o] = ll;
    }
}

// Per-head W transpose-split: z selects WQ/WK/WV slice; dst += z*E*E.
__global__ void k_tsplit3(const float* __restrict__ s0, const float* __restrict__ s1,
                          const float* __restrict__ s2,
                          u16* __restrict__ dh, u16* __restrict__ dl)
{
    const int E = 768; const long long EE = (long long)E * E;
    const float* s = (blockIdx.z == 0) ? s0 : (blockIdx.z == 1) ? s1 : s2;
    u16* h = dh + blockIdx.z * EE;
    u16* l = dl + blockIdx.z * EE;
    __shared__ float t[32][33];
    int tx = threadIdx.x & 31, ty = threadIdx.x >> 5;
    int kb = blockIdx.y << 5, nb_ = blockIdx.x << 5;
#pragma unroll
    for (int i = 0; i < 4; ++i)
        t[ty + 8 * i][tx] = s[(long long)(kb + ty + 8 * i) * E + nb_ + tx];
    __syncthreads();
#pragma unroll
    for (int i = 0; i < 4; ++i) {
        float v = t[tx][ty + 8 * i];
        long long o = (long long)(nb_ + ty + 8 * i) * E + kb + tx;
        u16 hh, ll; split2(v, hh, ll);
        h[o] = hh; l[o] = ll;
    }
}

// ---------------- 3-phase column softmax (query-axis) ----------------
__global__ __launch_bounds__(256)
void sm_part(const u16* __restrict__ Sh, const u16* __restrict__ Sl,
             float2* __restrict__ part, int T, float scale)
{
    const int lane = threadIdx.x & 63, seg = threadIdx.x >> 6;
    const int j0 = blockIdx.x * 256 + lane * 4;
    const long long base = (long long)blockIdx.z * T * T;
    const int rpc = T / RC, rps = rpc / 4;
    const int r0 = blockIdx.y * rpc + seg * rps;

    float m[4] = {-3.4e38f, -3.4e38f, -3.4e38f, -3.4e38f};
    float s[4] = {0.f, 0.f, 0.f, 0.f};
    for (int r = 0; r < rps; ++r) {
        long long o = base + (long long)(r0 + r) * T + j0;
        u16x4 vh = *(const u16x4*)(Sh + o);
        u16x4 vl = *(const u16x4*)(Sl + o);
#pragma unroll
        for (int c = 0; c < 4; ++c) {
            float v = (bf2f(vh[c]) + bf2f(vl[c])) * scale;
            float mn = fmaxf(m[c], v);
            s[c] = s[c] * __expf(m[c] - mn) + __expf(v - mn);
            m[c] = mn;
        }
    }
    __shared__ float4 smm[4][64], sss[4][64];
    smm[seg][lane] = make_float4(m[0], m[1], m[2], m[3]);
    sss[seg][lane] = make_float4(s[0], s[1], s[2], s[3]);
    __syncthreads();
    if (seg == 0) {
#pragma unroll
        for (int q = 1; q < 4; ++q) {
            float4 mq4 = smm[q][lane], sq4 = sss[q][lane];
            float mq[4] = {mq4.x, mq4.y, mq4.z, mq4.w};
            float sq[4] = {sq4.x, sq4.y, sq4.z, sq4.w};
#pragma unroll
            for (int c = 0; c < 4; ++c) {
                float mn = fmaxf(m[c], mq[c]);
                s[c] = s[c] * __expf(m[c] - mn) + sq[c] * __expf(mq[c] - mn);
                m[c] = mn;
            }
        }
        long long pb = ((long long)blockIdx.z * RC + blockIdx.y) * T + j0;
#pragma unroll
        for (int c = 0; c < 4; ++c)
            part[pb + c] = make_float2(m[c], s[c]);
    }
}

__global__ __launch_bounds__(256)
void sm_fin2(const float2* __restrict__ part, float2* __restrict__ fin, int T)
{
    int j = blockIdx.x * 256 + threadIdx.x;
    long long pb = (long long)blockIdx.y * RC * T + j;
    float mt = -3.4e38f, st = 0.f;
#pragma unroll
    for (int q = 0; q < RC; ++q) {
        float2 p = part[pb + (long long)q * T];
        float mn = fmaxf(mt, p.x);
        st = st * __expf(mt - mn) + p.y * __expf(p.x - mn);
        mt = mn;
    }
    fin[(long long)blockIdx.y * T + j] = make_float2(mt, 1.f / st);
}

__global__ __launch_bounds__(256)
void sm_norm(u16* __restrict__ Sh, u16* __restrict__ Sl,
             const float2* __restrict__ fin, int T, float scale)
{
    const int lane = threadIdx.x & 63, seg = threadIdx.x >> 6;
    const int j0 = blockIdx.x * 256 + lane * 4;
    const long long base = (long long)blockIdx.z * T * T;
    const int rpc = T / RC, rps = rpc / 4;
    const int r0 = blockIdx.y * rpc + seg * rps;
    float mt[4], inv[4];
#pragma unroll
    for (int c = 0; c < 4; ++c) {
        float2 f = fin[(long long)blockIdx.z * T + j0 + c];
        mt[c] = f.x; inv[c] = f.y;
    }
    for (int r = 0; r < rps; ++r) {
        long long o = base + (long long)(r0 + r) * T + j0;
        u16x4 vh = *(const u16x4*)(Sh + o);
        u16x4 vl = *(const u16x4*)(Sl + o);
        u16x4 oh, ol;
#pragma unroll
        for (int c = 0; c < 4; ++c) {
            float v = (bf2f(vh[c]) + bf2f(vl[c])) * scale;
            float p = __expf(v - mt[c]) * inv[c];
            u16 hh, ll; split2(p, hh, ll);
            oh[c] = hh; ol[c] = ll;
        }
        *(u16x4*)(Sh + o) = oh;
        *(u16x4*)(Sl + o) = ol;
    }
}

extern "C" void kernel_launch(void* const* d_in, const int* in_sizes, int n_in,
                              void* d_out, int out_size, void* d_ws, size_t ws_size,
                              hipStream_t stream)
{
    const float* x  = (const float*)d_in[0];   // (B,T,E)
    const float* WQ = (const float*)d_in[1];   // (H,E,E)
    const float* WK = (const float*)d_in[2];
    const float* WV = (const float*)d_in[3];
    const float* WO = (const float*)d_in[4];   // (H*E, E)
    float* out = (float*)d_out;                // (B,T,E)

    const int B = 8, T = 1024, E = 768, H = 12;
    const long long TE = (long long)T * E;     // 786432
    const long long TT = (long long)T * T;     // 1048576
    const long long HE = (long long)H * E;     // 9216
    const long long EE = (long long)E * E;

    // ---- workspace layout (bytes) ----
    char* p = (char*)d_ws;
    u16* Xh   = (u16*)p; p += (size_t)B * TE * 2;   // 12.6 MB
    u16* Xl   = (u16*)p; p += (size_t)B * TE * 2;
    u16* WOth = (u16*)p; p += (size_t)E * HE * 2;   // 14.2 MB (768 x 9216)
    u16* WOtl = (u16*)p; p += (size_t)E * HE * 2;
    u16* Wth  = (u16*)p; p += (size_t)3 * EE * 2;   // 3.5 MB (per-head, reused)
    u16* Wtl  = (u16*)p; p += (size_t)3 * EE * 2;
    u16* zp   = (u16*)p; p += 4096;                 // zero page for window OOB
    float2* part = (float2*)p; p += (size_t)B * RC * T * sizeof(float2); // 1 MB
    float2* finb = (float2*)p; p += (size_t)B * T * sizeof(float2);      // 64 KB
    size_t used = (size_t)(p - (char*)d_ws);
    // Slice: Q,K,V,Kt hi/lo pairs + S hi/lo.  Vt aliases K (K dead after
    // its transpose); Z aliases Q (Q dead after scores).
    size_t slice = (size_t)(8 * TE + 2 * TT) * 2;   // 16.8 MB
    int NC = (int)((ws_size - used) / slice);
    if (NC < 1) NC = 1;
    if (NC > B) NC = B;
    u16* Qh  = (u16*)p; p += (size_t)NC * TE * 2;
    u16* Ql  = (u16*)p; p += (size_t)NC * TE * 2;
    u16* Kh  = (u16*)p; p += (size_t)NC * TE * 2;
    u16* Kl  = (u16*)p; p += (size_t)NC * TE * 2;
    u16* Vh  = (u16*)p; p += (size_t)NC * TE * 2;
    u16* Vl  = (u16*)p; p += (size_t)NC * TE * 2;
    u16* Kth = (u16*)p; p += (size_t)NC * TE * 2;
    u16* Ktl = (u16*)p; p += (size_t)NC * TE * 2;
    u16* Sh  = (u16*)p; p += (size_t)NC * TT * 2;
    u16* Sl  = (u16*)p; p += (size_t)NC * TT * 2;
    u16* Zh = Qh;   // alias: Q dead after scores GEMM
    u16* Zl = Ql;
    u16* Vth = Kh;  // alias: K dead after its transpose
    u16* Vtl = Kl;

    hipMemsetAsync(out, 0, (size_t)B * TE * sizeof(float), stream);
    hipMemsetAsync(zp, 0, 4096, stream);

    dim3 blk(256);

    // One-time operand splits.
    k_split<<<2048, blk, 0, stream>>>(x, Xh, Xl, (long long)B * TE);
    k_tsplit<<<dim3(E / 32, (int)HE / 32), blk, 0, stream>>>(WO, WOth, WOtl, (int)HE, E);

    for (int h = 0; h < H; ++h) {
        // Quirky-reshape window: out row i reads Zc flat [i*9216,(i+1)*9216);
        // head h owns flat [h*786432,(h+1)*786432). Bounds multiples of 768.
        const int i_lo = (int)(((long long)h * TE) / HE);
        const long long aShift = (long long)i_lo * HE - (long long)h * TE;

        k_tsplit3<<<dim3(24, 24, 3), blk, 0, stream>>>(
            WQ + (size_t)h * EE, WK + (size_t)h * EE, WV + (size_t)h * EE, Wth, Wtl);

        for (int b0 = 0; b0 < B; b0 += NC) {
            const int nb = (B - b0 < NC) ? (B - b0) : NC;

            // Q/K/V projections: (nb*T x 768) @ (768 x 768), z innermost.
            g_qkv<<<dim3(18, nb * T / 128), blk, 0, stream>>>(
                Xh + (size_t)b0 * TE, Xl + (size_t)b0 * TE, Wth, Wtl,
                Qh, Ql, Kh, Kl, Vh, Vl);

            // Kt: transpose flat-(768,1024) view of K -> (1024,768).
            t_hl<<<dim3(16, 24, nb), blk, 0, stream>>>(Kh, Kl, Kth, Ktl, 768, 1024);
            // Vt: matrix transpose (1024,768) -> (768,1024), into K buffers.
            t_hl<<<dim3(12, 32, nb), blk, 0, stream>>>(Vh, Vl, Vth, Vtl, 1024, 768);

            // Scores: Q (1024x768) @ Kt^T, ldb=768.
            g_bt<<<dim3(8, 8, nb), blk, 0, stream>>>(
                Qh, Ql, Kth, Ktl, Sh, Sl, 768, 768, 768, 1024, TE, TE, TT);

            // Softmax over query axis, 1/sqrt(T) pre-scale, 3-phase.
            sm_part<<<dim3(T / 256, RC, nb), blk, 0, stream>>>(Sh, Sl, part, T, 0.03125f);
            sm_fin2<<<dim3(T / 256, nb), blk, 0, stream>>>(part, finb, T);
            sm_norm<<<dim3(T / 256, RC, nb), blk, 0, stream>>>(Sh, Sl, finb, T, 0.03125f);

            // Z = A (1024x1024) @ Vt^T, ldb=1024.  (Z aliases Q.)
            g_bt<<<dim3(6, 8, nb), blk, 0, stream>>>(
                Sh, Sl, Vth, Vtl, Zh, Zl, 1024, 1024, 1024, 768, TT, TE, TE);

            // Final projection, windowed A, k-split x24 + atomics.
            g_fin<<<dim3(6, 24, nb), blk, 0, stream>>>(
                Zh, Zl, WOth, WOtl,
                out + (size_t)b0 * TE + (size_t)i_lo * E, zp,
                aShift, T - i_lo, 24);
        }
    }
}

// Round 6
// 4305.062 us; speedup vs baseline: 1.0081x; 1.0081x over previous
//
#include <hip/hip_runtime.h>

// B=8, T=1024, E=768, H=12.
// Round 10: merged final projection. Z for all 12 heads is written into
// Zall in (h,t,dv)-flat layout; the quirky reshape makes out[b] exactly
// reshape(Zall_b,(1024,9216)) @ WO -> ONE dense GEMM per chunk (g_out,
// k-split 2) replacing 12 windowed g_fin launches (24-way atomics, ~900MB
// RMW traffic, 33% zero-page rows). Adaptive: falls back to the r9 windowed
// path if ws_size can't hold Zall. GEMM core unchanged (806 TF-issued,
// ~92% of the m97-structure ceiling).

typedef __bf16 bf16x8 __attribute__((ext_vector_type(8)));
typedef float  f32x4  __attribute__((ext_vector_type(4)));
typedef unsigned short u16;
typedef u16 u16x2 __attribute__((ext_vector_type(2)));
typedef u16 u16x4 __attribute__((ext_vector_type(4)));
typedef unsigned int u32;

#define RC 16   // row-chunks for 3-phase softmax

__device__ __forceinline__ float bf2f(u16 u) {
    union { u32 i; float f; } x; x.i = ((u32)u) << 16; return x.f;
}
__device__ __forceinline__ u16 f2bf(float f) {
    __bf16 h = (__bf16)f; union { __bf16 b; u16 u; } x; x.b = h; return x.u;
}
__device__ __forceinline__ void split2(float v, u16& h, u16& l) {
    h = f2bf(v); l = f2bf(v - bf2f(h));
}

__device__ __forceinline__ void gl16(const void* g, void* l) {
    __builtin_amdgcn_global_load_lds(
        (const __attribute__((address_space(1))) u32*)g,
        (__attribute__((address_space(3))) u32*)l, 16, 0, 0);
}

// ---------------- 128x128 split-bf16 core (B^T row-major only) ----------
// A: hi/lo row-major (M x K, lda). B^T: hi/lo row-major (N x K, ldb).
// Both staged via global_load_lds w16, source k pre-swizzled so the
// ds_read_b128 fragment reads are bank-even (verified conflict-free r4).
// WIN=1: per-lane A-source clamp to zero page for the quirky flat window.
template<int WIN>
__device__ __forceinline__ void core(
    const u16* __restrict__ Ah, const u16* __restrict__ Al,
    const u16* __restrict__ Bh, const u16* __restrict__ Bl,
    float* __restrict__ C, u16* __restrict__ Ch, u16* __restrict__ Cl,
    int K, int lda, int ldb, int ldc,
    long long aShift, long long aHi, const u16* __restrict__ zp,
    int mClip, int mode, int mtile, int kChunk, int kChunks, int n0)
{
    __shared__ u16 Ahs[4096], Als[4096], Bhs[4096], Bls[4096]; // 32 KiB

    const int tid = threadIdx.x, lane = tid & 63, w = tid >> 6;
    const int m0 = mtile * 128;
    const int wm = (w & 1) << 6, wn = (w >> 1) << 6;
    const int lr = lane & 15, lq = lane >> 4;
    const int rs = (lr >> 1) & 3;
    const int fro = (lq ^ rs) << 4;            // frag byte offset in row

    // DMA staging geometry: wave w covers LDS rows w*16..+15 (call 0)
    // and +64 (call 1); lane -> (row, 16B slot). Source k pre-swizzled.
    const int srow = (w << 4) + (lane >> 2);
    const int kk = (((lane & 3) ^ ((srow >> 1) & 3)) << 3);
    const int lds0 = (w << 10), lds1 = lds0 + 4096;

    f32x4 acc[4][4] = {};
    const int kLen = K / kChunks;
    const int kBeg = kChunk * kLen, kEnd = kBeg + kLen;

    auto stage = [&](int k0) {
        long long o1 = (long long)(m0 + srow) * lda + k0 + kk;
        long long o2 = o1 + (long long)64 * lda;
        const u16 *p1h = Ah + o1, *p1l = Al + o1;
        const u16 *p2h = Ah + o2, *p2l = Al + o2;
        if constexpr (WIN) {
            long long a1 = o1 + aShift, a2 = o2 + aShift;
            bool v1 = (a1 >= 0) && (a1 < aHi);
            bool v2 = (a2 >= 0) && (a2 < aHi);
            p1h = v1 ? Ah + a1 : zp;  p1l = v1 ? Al + a1 : zp;
            p2h = v2 ? Ah + a2 : zp;  p2l = v2 ? Al + a2 : zp;
        }
        gl16(p1h, (char*)Ahs + lds0);  gl16(p2h, (char*)Ahs + lds1);
        gl16(p1l, (char*)Als + lds0);  gl16(p2l, (char*)Als + lds1);
        long long b1 = (long long)(n0 + srow) * ldb + k0 + kk;
        long long b2 = b1 + (long long)64 * ldb;
        gl16(Bh + b1, (char*)Bhs + lds0);  gl16(Bh + b2, (char*)Bhs + lds1);
        gl16(Bl + b1, (char*)Bls + lds0);  gl16(Bl + b2, (char*)Bls + lds1);
    };

    for (int k0 = kBeg; k0 < kEnd; k0 += 32) {
        stage(k0);                       // async DMA into LDS
        __syncthreads();                 // drains vmcnt + lgkmcnt

        bf16x8 a_h[4], a_l[4];
#pragma unroll
        for (int mi = 0; mi < 4; ++mi) {
            int off = ((wm + (mi << 4) + lr) << 6) + fro;
            a_h[mi] = *(const bf16x8*)((char*)Ahs + off);
            a_l[mi] = *(const bf16x8*)((char*)Als + off);
        }
#pragma unroll
        for (int ni = 0; ni < 4; ++ni) {
            int off = ((wn + (ni << 4) + lr) << 6) + fro;
            bf16x8 b_h = *(const bf16x8*)((char*)Bhs + off);
            bf16x8 b_l = *(const bf16x8*)((char*)Bls + off);
#pragma unroll
            for (int mi = 0; mi < 4; ++mi) {
                acc[mi][ni] = __builtin_amdgcn_mfma_f32_16x16x32_bf16(a_h[mi], b_h, acc[mi][ni], 0, 0, 0);
                acc[mi][ni] = __builtin_amdgcn_mfma_f32_16x16x32_bf16(a_l[mi], b_h, acc[mi][ni], 0, 0, 0);
                acc[mi][ni] = __builtin_amdgcn_mfma_f32_16x16x32_bf16(a_h[mi], b_l, acc[mi][ni], 0, 0, 0);
            }
        }
        __syncthreads();
    }

    // Epilogue: C/D layout col = lane&15, row = (lane>>4)*4 + reg  [m89]
#pragma unroll
    for (int mi = 0; mi < 4; ++mi)
#pragma unroll
        for (int r = 0; r < 4; ++r) {
            int row = m0 + wm + (mi << 4) + (lq << 2) + r;
            if (row < mClip) {
#pragma unroll
                for (int ni = 0; ni < 4; ++ni) {
                    long long off = (long long)row * ldc + n0 + wn + (ni << 4) + lr;
                    float v = acc[mi][ni][r];
                    if (mode == 2)      atomicAdd(&C[off], v);
                    else if (mode == 1) { u16 hh, ll; split2(v, hh, ll); Ch[off] = hh; Cl[off] = ll; }
                    else                C[off] = v;
                }
            }
        }
}

// Fused QKV: grid (18, M/128); x = n-tile*3 + z (z innermost so the 18
// blocks sharing an A-panel dispatch adjacently across XCDs).
__global__ __launch_bounds__(256, 4)
void g_qkv(const u16* __restrict__ Xh, const u16* __restrict__ Xl,
           const u16* __restrict__ Wth, const u16* __restrict__ Wtl,
           u16* __restrict__ Qh, u16* __restrict__ Ql,
           u16* __restrict__ Kh, u16* __restrict__ Kl,
           u16* __restrict__ Vh, u16* __restrict__ Vl)
{
    const long long EE = 768LL * 768;
    int z  = blockIdx.x % 3;
    int n0 = (blockIdx.x / 3) * 128;
    const u16* bh = Wth + (long long)z * EE;
    const u16* bl = Wtl + (long long)z * EE;
    u16* ch = (z == 0) ? Qh : (z == 1) ? Kh : Vh;
    u16* cl = (z == 0) ? Ql : (z == 1) ? Kl : Vl;
    core<0>(Xh, Xl, bh, bl, nullptr, ch, cl, 768, 768, 768, 768,
            0, 0, nullptr, 1 << 30, 1, blockIdx.y, 0, 1, n0);
}

// Generic B^T GEMM (scores: B=Kt; Z: B=Vt), batched via z.
__global__ __launch_bounds__(256, 4)
void g_bt(const u16* __restrict__ Ah, const u16* __restrict__ Al,
          const u16* __restrict__ Bh, const u16* __restrict__ Bl,
          u16* __restrict__ Ch, u16* __restrict__ Cl,
          int K, int lda, int ldb, int ldc,
          long long sA, long long sB, long long sC)
{
    long long z = blockIdx.z;
    core<0>(Ah + z * sA, Al + z * sA, Bh + z * sB, Bl + z * sB,
            nullptr, Ch + z * sC, Cl + z * sC,
            K, lda, ldb, ldc, 0, 0, nullptr, 1 << 30, 1,
            blockIdx.y, 0, 1, blockIdx.x * 128);
}

// Merged final projection: out[b] = reshape(Zall_b,(1024,9216)) @ WO.
// grid (6, 8*kChunks, nb); mode 2 (atomic add of k-chunk partials).
__global__ __launch_bounds__(256, 4)
void g_out(const u16* __restrict__ Zh, const u16* __restrict__ Zl,
           const u16* __restrict__ WOth, const u16* __restrict__ WOtl,
           float* __restrict__ C, int kChunks)
{
    const long long ZB = 12LL * 786432;   // per-batch Zall stride (elems)
    long long z = blockIdx.z;
    int mtile = blockIdx.y / kChunks;
    int kc    = blockIdx.y % kChunks;
    core<0>(Zh + z * ZB, Zl + z * ZB, WOth, WOtl, C + z * 786432LL,
            nullptr, nullptr, 9216, 9216, 9216, 768,
            0, 0, nullptr, 1 << 30, 2, mtile, kc, kChunks, blockIdx.x * 128);
}

// Fallback final projection: windowed A (quirky flat reshape), k-split + atomics.
__global__ __launch_bounds__(256, 4)
void g_fin(const u16* __restrict__ Zh, const u16* __restrict__ Zl,
           const u16* __restrict__ WOth, const u16* __restrict__ WOtl,
           float* __restrict__ C, const u16* __restrict__ zp,
           long long aShift, int mClip, int kChunks)
{
    const long long TE_ = 786432;
    long long z = blockIdx.z;
    core<1>(Zh + z * TE_, Zl + z * TE_, WOth, WOtl, C + z * TE_,
            nullptr, nullptr, 9216, 9216, 9216, 768,
            aShift, TE_, zp, mClip, 2, 0, blockIdx.y, kChunks, blockIdx.x * 128);
}

// Batched flat transpose of hi/lo u16 buffers: out[c*R+r] = in[r*C+c].
// Tile 32(rows) x 64(cols); u16x2 loads/stores. grid (C/64, R/32, nb).
__global__ __launch_bounds__(256)
void t_hl(const u16* __restrict__ ih, const u16* __restrict__ il,
          u16* __restrict__ oh, u16* __restrict__ ol, int R, int C)
{
    long long zo = (long long)blockIdx.z * R * C;
    __shared__ u16 L[64][34];
    const int t = threadIdx.x, tx = t & 31, ty = t >> 5;
    const int r0 = blockIdx.y * 32, c0 = blockIdx.x * 64;
    const int orow = t >> 2;

    const u16* iv[2] = { ih + zo, il + zo };
    u16* ov[2] = { oh + zo, ol + zo };
#pragma unroll
    for (int p = 0; p < 2; ++p) {
        const u16* in = iv[p];  u16* out = ov[p];
#pragma unroll
        for (int i = 0; i < 4; ++i) {
            u16x2 v = *(const u16x2*)&in[(long long)(r0 + ty + 8 * i) * C + c0 + tx * 2];
            L[tx * 2][ty + 8 * i] = v[0];
            L[tx * 2 + 1][ty + 8 * i] = v[1];
        }
        __syncthreads();
#pragma unroll
        for (int i = 0; i < 4; ++i) {
            int j = (t & 3) * 4 + i;
            u16x2 wv;
            wv[0] = L[orow][j * 2];
            wv[1] = L[orow][j * 2 + 1];
            *(u16x2*)&out[(long long)(c0 + orow) * R + r0 + j * 2] = wv;
        }
        __syncthreads();
    }
}

// fp32 -> (hi,lo) bf16, flat.
__global__ void k_split(const float* __restrict__ s, u16* __restrict__ h,
                        u16* __restrict__ l, long long n)
{
    long long i = ((long long)blockIdx.x * blockDim.x + threadIdx.x) * 4;
    long long stride = (long long)gridDim.x * blockDim.x * 4;
    for (; i < n; i += stride) {
        float4 v = *(const float4*)(s + i);
        u16x4 hh, ll;
        u16 h0, l0, h1, l1, h2, l2, h3, l3;
        split2(v.x, h0, l0); split2(v.y, h1, l1);
        split2(v.z, h2, l2); split2(v.w, h3, l3);
        hh[0] = h0; hh[1] = h1; hh[2] = h2; hh[3] = h3;
        ll[0] = l0; ll[1] = l1; ll[2] = l2; ll[3] = l3;
        *(u16x4*)(h + i) = hh;
        *(u16x4*)(l + i) = ll;
    }
}

// fp32 (Ks x Ns) -> transposed (Ns x Ks) hi/lo bf16.
__global__ void k_tsplit(const float* __restrict__ s, u16* __restrict__ dh,
                         u16* __restrict__ dl, int Ks, int Ns)
{
    __shared__ float t[32][33];
    int tx = threadIdx.x & 31, ty = threadIdx.x >> 5;
    int kb = blockIdx.y << 5, nb_ = blockIdx.x << 5;
#pragma unroll
    for (int i = 0; i < 4; ++i)
        t[ty + 8 * i][tx] = s[(long long)(kb + ty + 8 * i) * Ns + nb_ + tx];
    __syncthreads();
#pragma unroll
    for (int i = 0; i < 4; ++i) {
        float v = t[tx][ty + 8 * i];
        long long o = (long long)(nb_ + ty + 8 * i) * Ks + kb + tx;
        u16 hh, ll; split2(v, hh, ll);
        dh[o] = hh; dl[o] = ll;
    }
}

// Per-head W transpose-split: z selects WQ/WK/WV slice; dst += z*E*E.
__global__ void k_tsplit3(const float* __restrict__ s0, const float* __restrict__ s1,
                          const float* __restrict__ s2,
                          u16* __restrict__ dh, u16* __restrict__ dl)
{
    const int E = 768; const long long EE = (long long)E * E;
    const float* s = (blockIdx.z == 0) ? s0 : (blockIdx.z == 1) ? s1 : s2;
    u16* h = dh + blockIdx.z * EE;
    u16* l = dl + blockIdx.z * EE;
    __shared__ float t[32][33];
    int tx = threadIdx.x & 31, ty = threadIdx.x >> 5;
    int kb = blockIdx.y << 5, nb_ = blockIdx.x << 5;
#pragma unroll
    for (int i = 0; i < 4; ++i)
        t[ty + 8 * i][tx] = s[(long long)(kb + ty + 8 * i) * E + nb_ + tx];
    __syncthreads();
#pragma unroll
    for (int i = 0; i < 4; ++i) {
        float v = t[tx][ty + 8 * i];
        long long o = (long long)(nb_ + ty + 8 * i) * E + kb + tx;
        u16 hh, ll; split2(v, hh, ll);
        h[o] = hh; l[o] = ll;
    }
}

// ---------------- 3-phase column softmax (query-axis) ----------------
__global__ __launch_bounds__(256)
void sm_part(const u16* __restrict__ Sh, const u16* __restrict__ Sl,
             float2* __restrict__ part, int T, float scale)
{
    const int lane = threadIdx.x & 63, seg = threadIdx.x >> 6;
    const int j0 = blockIdx.x * 256 + lane * 4;
    const long long base = (long long)blockIdx.z * T * T;
    const int rpc = T / RC, rps = rpc / 4;
    const int r0 = blockIdx.y * rpc + seg * rps;

    float m[4] = {-3.4e38f, -3.4e38f, -3.4e38f, -3.4e38f};
    float s[4] = {0.f, 0.f, 0.f, 0.f};
    for (int r = 0; r < rps; ++r) {
        long long o = base + (long long)(r0 + r) * T + j0;
        u16x4 vh = *(const u16x4*)(Sh + o);
        u16x4 vl = *(const u16x4*)(Sl + o);
#pragma unroll
        for (int c = 0; c < 4; ++c) {
            float v = (bf2f(vh[c]) + bf2f(vl[c])) * scale;
            float mn = fmaxf(m[c], v);
            s[c] = s[c] * __expf(m[c] - mn) + __expf(v - mn);
            m[c] = mn;
        }
    }
    __shared__ float4 smm[4][64], sss[4][64];
    smm[seg][lane] = make_float4(m[0], m[1], m[2], m[3]);
    sss[seg][lane] = make_float4(s[0], s[1], s[2], s[3]);
    __syncthreads();
    if (seg == 0) {
#pragma unroll
        for (int q = 1; q < 4; ++q) {
            float4 mq4 = smm[q][lane], sq4 = sss[q][lane];
            float mq[4] = {mq4.x, mq4.y, mq4.z, mq4.w};
            float sq[4] = {sq4.x, sq4.y, sq4.z, sq4.w};
#pragma unroll
            for (int c = 0; c < 4; ++c) {
                float mn = fmaxf(m[c], mq[c]);
                s[c] = s[c] * __expf(m[c] - mn) + sq[c] * __expf(mq[c] - mn);
                m[c] = mn;
            }
        }
        long long pb = ((long long)blockIdx.z * RC + blockIdx.y) * T + j0;
#pragma unroll
        for (int c = 0; c < 4; ++c)
            part[pb + c] = make_float2(m[c], s[c]);
    }
}

__global__ __launch_bounds__(256)
void sm_fin2(const float2* __restrict__ part, float2* __restrict__ fin, int T)
{
    int j = blockIdx.x * 256 + threadIdx.x;
    long long pb = (long long)blockIdx.y * RC * T + j;
    float mt = -3.4e38f, st = 0.f;
#pragma unroll
    for (int q = 0; q < RC; ++q) {
        float2 p = part[pb + (long long)q * T];
        float mn = fmaxf(mt, p.x);
        st = st * __expf(mt - mn) + p.y * __expf(p.x - mn);
        mt = mn;
    }
    fin[(long long)blockIdx.y * T + j] = make_float2(mt, 1.f / st);
}

__global__ __launch_bounds__(256)
void sm_norm(u16* __restrict__ Sh, u16* __restrict__ Sl,
             const float2* __restrict__ fin, int T, float scale)
{
    const int lane = threadIdx.x & 63, seg = threadIdx.x >> 6;
    const int j0 = blockIdx.x * 256 + lane * 4;
    const long long base = (long long)blockIdx.z * T * T;
    const int rpc = T / RC, rps = rpc / 4;
    const int r0 = blockIdx.y * rpc + seg * rps;
    float mt[4], inv[4];
#pragma unroll
    for (int c = 0; c < 4; ++c) {
        float2 f = fin[(long long)blockIdx.z * T + j0 + c];
        mt[c] = f.x; inv[c] = f.y;
    }
    for (int r = 0; r < rps; ++r) {
        long long o = base + (long long)(r0 + r) * T + j0;
        u16x4 vh = *(const u16x4*)(Sh + o);
        u16x4 vl = *(const u16x4*)(Sl + o);
        u16x4 oh, ol;
#pragma unroll
        for (int c = 0; c < 4; ++c) {
            float v = (bf2f(vh[c]) + bf2f(vl[c])) * scale;
            float p = __expf(v - mt[c]) * inv[c];
            u16 hh, ll; split2(p, hh, ll);
            oh[c] = hh; ol[c] = ll;
        }
        *(u16x4*)(Sh + o) = oh;
        *(u16x4*)(Sl + o) = ol;
    }
}

extern "C" void kernel_launch(void* const* d_in, const int* in_sizes, int n_in,
                              void* d_out, int out_size, void* d_ws, size_t ws_size,
                              hipStream_t stream)
{
    const float* x  = (const float*)d_in[0];   // (B,T,E)
    const float* WQ = (const float*)d_in[1];   // (H,E,E)
    const float* WK = (const float*)d_in[2];
    const float* WV = (const float*)d_in[3];
    const float* WO = (const float*)d_in[4];   // (H*E, E)
    float* out = (float*)d_out;                // (B,T,E)

    const int B = 8, T = 1024, E = 768, H = 12;
    const long long TE = (long long)T * E;     // 786432
    const long long TT = (long long)T * T;     // 1048576
    const long long HE = (long long)H * E;     // 9216
    const long long EE = (long long)E * E;

    // ---- workspace layout (bytes) ----
    char* p = (char*)d_ws;
    u16* Xh   = (u16*)p; p += (size_t)B * TE * 2;   // 12.6 MB
    u16* Xl   = (u16*)p; p += (size_t)B * TE * 2;
    u16* WOth = (u16*)p; p += (size_t)E * HE * 2;   // 14.2 MB (768 x 9216)
    u16* WOtl = (u16*)p; p += (size_t)E * HE * 2;
    u16* Wth  = (u16*)p; p += (size_t)3 * EE * 2;   // 3.5 MB (per-head, reused)
    u16* Wtl  = (u16*)p; p += (size_t)3 * EE * 2;
    u16* zp   = (u16*)p; p += 4096;                 // zero page for window OOB
    float2* part = (float2*)p; p += (size_t)B * RC * T * sizeof(float2); // 1 MB
    float2* finb = (float2*)p; p += (size_t)B * T * sizeof(float2);      // 64 KB
    size_t used = (size_t)(p - (char*)d_ws);

    // Per-batch working slice: Q,K,V,Kt hi/lo + S hi/lo (Vt aliases K).
    size_t slice  = (size_t)(8 * TE + 2 * TT) * 2;  // 16.8 MB
    size_t zslice = (size_t)12 * TE * 4;            // Zall per batch: 37.7 MB
    int NC = (int)((ws_size - used) / slice);
    if (NC < 1) NC = 1;
    if (NC > B) NC = B;
    // Tier A (merged final) only if Zall fits WITHOUT shrinking the chunk.
    int NC_A = (int)((ws_size - used) / (slice + zslice));
    if (NC_A > B) NC_A = B;
    const bool tierA = (NC_A >= NC);

    u16* Qh  = (u16*)p; p += (size_t)NC * TE * 2;
    u16* Ql  = (u16*)p; p += (size_t)NC * TE * 2;
    u16* Kh  = (u16*)p; p += (size_t)NC * TE * 2;
    u16* Kl  = (u16*)p; p += (size_t)NC * TE * 2;
    u16* Vh  = (u16*)p; p += (size_t)NC * TE * 2;
    u16* Vl  = (u16*)p; p += (size_t)NC * TE * 2;
    u16* Kth = (u16*)p; p += (size_t)NC * TE * 2;
    u16* Ktl = (u16*)p; p += (size_t)NC * TE * 2;
    u16* Sh  = (u16*)p; p += (size_t)NC * TT * 2;
    u16* Sl  = (u16*)p; p += (size_t)NC * TT * 2;
    u16* Zallh = (u16*)p; if (tierA) p += (size_t)NC * 12 * TE * 2;
    u16* Zalll = (u16*)p;
    u16* Zh = Qh;   // fallback alias: Q dead after scores GEMM
    u16* Zl = Ql;
    u16* Vth = Kh;  // alias: K dead after its transpose
    u16* Vtl = Kl;

    hipMemsetAsync(out, 0, (size_t)B * TE * sizeof(float), stream);
    hipMemsetAsync(zp, 0, 4096, stream);

    dim3 blk(256);

    // One-time operand splits.
    k_split<<<2048, blk, 0, stream>>>(x, Xh, Xl, (long long)B * TE);
    k_tsplit<<<dim3(E / 32, (int)HE / 32), blk, 0, stream>>>(WO, WOth, WOtl, (int)HE, E);

    for (int b0 = 0; b0 < B; b0 += NC) {
        const int nb = (B - b0 < NC) ? (B - b0) : NC;

        for (int h = 0; h < H; ++h) {
            k_tsplit3<<<dim3(24, 24, 3), blk, 0, stream>>>(
                WQ + (size_t)h * EE, WK + (size_t)h * EE, WV + (size_t)h * EE, Wth, Wtl);

            // Q/K/V projections: (nb*T x 768) @ (768 x 768), z innermost.
            g_qkv<<<dim3(18, nb * T / 128), blk, 0, stream>>>(
                Xh + (size_t)b0 * TE, Xl + (size_t)b0 * TE, Wth, Wtl,
                Qh, Ql, Kh, Kl, Vh, Vl);

            // Kt: transpose flat-(768,1024) view of K -> (1024,768).
            t_hl<<<dim3(16, 24, nb), blk, 0, stream>>>(Kh, Kl, Kth, Ktl, 768, 1024);
            // Vt: matrix transpose (1024,768) -> (768,1024), into K buffers.
            t_hl<<<dim3(12, 32, nb), blk, 0, stream>>>(Vh, Vl, Vth, Vtl, 1024, 768);

            // Scores: Q (1024x768) @ Kt^T, ldb=768.
            g_bt<<<dim3(8, 8, nb), blk, 0, stream>>>(
                Qh, Ql, Kth, Ktl, Sh, Sl, 768, 768, 768, 1024, TE, TE, TT);

            // Softmax over query axis, 1/sqrt(T) pre-scale, 3-phase.
            sm_part<<<dim3(T / 256, RC, nb), blk, 0, stream>>>(Sh, Sl, part, T, 0.03125f);
            sm_fin2<<<dim3(T / 256, nb), blk, 0, stream>>>(part, finb, T);
            sm_norm<<<dim3(T / 256, RC, nb), blk, 0, stream>>>(Sh, Sl, finb, T, 0.03125f);

            if (tierA) {
                // Z -> Zall[b][h][t][dv]: C base +h*TE, batch stride 12*TE.
                g_bt<<<dim3(6, 8, nb), blk, 0, stream>>>(
                    Sh, Sl, Vth, Vtl,
                    Zallh + (size_t)h * TE, Zalll + (size_t)h * TE,
                    1024, 1024, 1024, 768, TT, TE, 12 * TE);
            } else {
                // Z = A @ Vt^T into Q alias, then windowed final per head.
                const int i_lo = (int)(((long long)h * TE) / HE);
                const long long aShift = (long long)i_lo * HE - (long long)h * TE;
                g_bt<<<dim3(6, 8, nb), blk, 0, stream>>>(
                    Sh, Sl, Vth, Vtl, Zh, Zl, 1024, 1024, 1024, 768, TT, TE, TE);
                g_fin<<<dim3(6, 24, nb), blk, 0, stream>>>(
                    Zh, Zl, WOth, WOtl,
                    out + (size_t)b0 * TE + (size_t)i_lo * E, zp,
                    aShift, T - i_lo, 24);
            }
        }

        if (tierA) {
            // Merged final: out[b] = reshape(Zall_b,(1024,9216)) @ WO.
            g_out<<<dim3(6, 8 * 2, nb), blk, 0, stream>>>(
                Zallh, Zalll, WOth, WOtl, out + (size_t)b0 * TE, 2);
        }
    }
}